// Round 1
// baseline (276.760 us; speedup 1.0000x reference)
//
#include <hip/hip_runtime.h>
#include <cmath>

// Problem constants (fixed by the reference)
#define SS 8192
#define BB 64
#define DD 64
#define CH 128          // cumsum chunk length
#define NCH 64          // SS / CH

// ws layout (floats):
//   rhs      [SS][64]   @ 0          (524288)
//   dtp      [SS][64]   @ 524288     (524288)   dt * inclusive-cumsum(rhs)
//   chunksum [NCH][64]  @ 1048576    (4096)
//   chunkoff [NCH][64]  @ 1052672    (4096)
//   Gd       [64]       @ 1056768    (64)       sum_s dtp[s,i]
// total ~4.23 MB

// ---------------- Kernel A: rhs[s,:] = MLP([t_s, 0...0]) for s=1..SS-1 ----------------
__global__ __launch_bounds__(256) void k_rhs(
    const float* __restrict__ t,
    const float* __restrict__ W1, const float* __restrict__ b1,
    const float* __restrict__ W2, const float* __restrict__ b2,
    const float* __restrict__ W3, const float* __restrict__ b3,
    const float* __restrict__ W4, const float* __restrict__ b4,
    float* __restrict__ rhs)
{
    __shared__ float sW1[64], sb1[64], sb2[128], sb3[64], sb4[64];
    __shared__ float sW2[64 * 128];
    __shared__ float sW3[128 * 64];
    __shared__ float sW4[64 * 64];
    __shared__ float sh1[4][64], sh2[4][128], sh3[4][64];

    const int tid = threadIdx.x;
    for (int i = tid; i < 64; i += 256) { sW1[i] = W1[i]; sb1[i] = b1[i]; sb3[i] = b3[i]; sb4[i] = b4[i]; }
    for (int i = tid; i < 128; i += 256) sb2[i] = b2[i];
    for (int i = tid; i < 64 * 128; i += 256) { sW2[i] = W2[i]; sW3[i] = W3[i]; }
    for (int i = tid; i < 64 * 64; i += 256) sW4[i] = W4[i];
    __syncthreads();

    const int w = tid >> 6, lane = tid & 63;
    const int waveg = blockIdx.x * 4 + w;
    const int nw = gridDim.x * 4;
    const int niter = (SS - 1 + nw - 1) / nw;   // uniform across block -> barriers safe

    for (int it = 0; it < niter; ++it) {
        const int s = 1 + waveg + it * nw;
        const bool valid = (s < SS);
        const float tv = valid ? t[s] : 0.f;   // t identical across batch; use row 0

        sh1[w][lane] = tanhf(tv * sW1[lane] + sb1[lane]);
        __syncthreads();

        float a0 = sb2[lane], a1 = sb2[lane + 64];
        #pragma unroll 8
        for (int i = 0; i < 64; ++i) {
            const float h = sh1[w][i];
            a0 = fmaf(h, sW2[i * 128 + lane], a0);
            a1 = fmaf(h, sW2[i * 128 + lane + 64], a1);
        }
        sh2[w][lane] = tanhf(a0);
        sh2[w][lane + 64] = tanhf(a1);
        __syncthreads();

        float a = sb3[lane];
        #pragma unroll 8
        for (int i = 0; i < 128; ++i) a = fmaf(sh2[w][i], sW3[i * 64 + lane], a);
        sh3[w][lane] = tanhf(a);
        __syncthreads();

        float r = sb4[lane];
        #pragma unroll 8
        for (int i = 0; i < 64; ++i) r = fmaf(sh3[w][i], sW4[i * 64 + lane], r);
        if (valid) rhs[s * 64 + lane] = r;
        __syncthreads();   // protect sh1/sh2/sh3 reuse next iter
    }
    if (blockIdx.x == 0 && tid < 64) rhs[tid] = 0.f;   // rhs row s=0 := 0
}

// ---------------- Kernel B: per-chunk column sums ----------------
__global__ __launch_bounds__(64) void k_csum(const float* __restrict__ rhs, float* __restrict__ chunksum)
{
    const int c = blockIdx.x, lane = threadIdx.x;
    const float* p = rhs + c * CH * 64 + lane;
    float s = 0.f;
    for (int j = 0; j < CH; ++j) s += p[j * 64];
    chunksum[c * 64 + lane] = s;
}

// ---------------- Kernel C: exclusive scan of chunk sums (+ zero Gd) ----------------
__global__ __launch_bounds__(64) void k_scan(const float* __restrict__ chunksum,
                                             float* __restrict__ chunkoff, float* __restrict__ Gd)
{
    const int lane = threadIdx.x;
    float run = 0.f;
    for (int c = 0; c < NCH; ++c) { chunkoff[c * 64 + lane] = run; run += chunksum[c * 64 + lane]; }
    Gd[lane] = 0.f;
}

// ---------------- Kernel D: dtp[s,i] = dt * inclusive-cumsum(rhs)[s,i]; Gd accumulate ----------------
__global__ __launch_bounds__(64) void k_dtp(const float* __restrict__ t, const float* __restrict__ rhs,
                                            const float* __restrict__ chunkoff,
                                            float* __restrict__ dtp, float* __restrict__ Gd)
{
    const int c = blockIdx.x, lane = threadIdx.x;
    const float dt = t[1] - t[0];
    float run = chunkoff[c * 64 + lane];
    float acc = 0.f;
    const float* p = rhs + c * CH * 64 + lane;
    float* q = dtp + c * CH * 64 + lane;
    for (int j = 0; j < CH; ++j) {
        run += p[j * 64];
        const float v = dt * run;
        q[j * 64] = v;
        acc += v;
    }
    atomicAdd(&Gd[lane], acc);
}

// ---------------- Kernel E: sol[b,s,:] = y0[b,:] + dtp[s,:]  (the big write) ----------------
__global__ __launch_bounds__(256) void k_sol(const float4* __restrict__ y0,
                                             const float4* __restrict__ dtp,
                                             float4* __restrict__ out)
{
    const int total4 = BB * SS * 16;   // 8388608 float4
    for (int idx = blockIdx.x * 256 + threadIdx.x; idx < total4; idx += gridDim.x * 256) {
        const int i4 = idx & 15;
        const int s  = (idx >> 4) & (SS - 1);
        const int b  = idx >> 17;           // 16 * 8192 = 2^17
        const float4 y = y0[b * 16 + i4];
        const float4 p = dtp[s * 16 + i4];
        float4 o;
        o.x = y.x + p.x; o.y = y.y + p.y; o.z = y.z + p.z; o.w = y.w + p.w;
        out[idx] = o;
    }
}

// ---------------- Kernel F: analytic conv-mean features + hurst head ----------------
__global__ __launch_bounds__(64) void k_feat(
    const float* __restrict__ y0, const float* __restrict__ dtp, const float* __restrict__ Gd,
    const float* __restrict__ K3, const float* __restrict__ c3,
    const float* __restrict__ K5, const float* __restrict__ c5,
    const float* __restrict__ K7, const float* __restrict__ c7,
    const float* __restrict__ K11, const float* __restrict__ c11,
    const float* __restrict__ H1, const float* __restrict__ hb1,
    const float* __restrict__ H2, const float* __restrict__ hb2,
    float* __restrict__ hurst)
{
    __shared__ float tot[64], sy0[64], hs[6][64], ts[6][64], feat[64];
    const int b = blockIdx.x, lane = threadIdx.x;

    const float y = y0[b * 64 + lane];
    sy0[lane] = y;
    tot[lane] = (float)SS * y + Gd[lane];   // sum_s sol[b,s,lane]
    float run = 0.f;
    hs[0][lane] = 0.f;
    for (int d = 1; d <= 5; ++d) { run += dtp[(d - 1) * 64 + lane]; hs[d][lane] = run; }
    run = 0.f;
    ts[0][lane] = 0.f;
    for (int d = 1; d <= 5; ++d) { run += dtp[(SS - d) * 64 + lane]; ts[d][lane] = run; }
    __syncthreads();

    // mean_s conv = (1/S) * sum_{i,j} K[o,i,j] * (tot[i] - edge corr(d=j-p)) + c[o]
    float acc = 0.f;
    const float cbias = c3[lane] + c5[lane] + c7[lane] + c11[lane];
    const float* Ks[4] = {K3, K5, K7, K11};
    const int kk[4] = {3, 5, 7, 11};
    for (int kn = 0; kn < 4; ++kn) {
        const float* K = Ks[kn];
        const int k = kk[kn], p = k >> 1;
        for (int i = 0; i < 64; ++i) {
            const float ti = tot[i], yi = sy0[i];
            const float* Kr = K + (lane * 64 + i) * k;
            for (int j = 0; j < k; ++j) {
                const int d = j - p;
                float corr = 0.f;
                if (d > 0)      corr = d * yi + hs[d][i];
                else if (d < 0) corr = (-d) * yi + ts[-d][i];
                acc = fmaf(Kr[j], ti - corr, acc);
            }
        }
    }
    feat[lane] = 0.25f * (acc * (1.0f / SS) + cbias);
    __syncthreads();

    // hurst = sigmoid(relu(feat @ H1 + hb1) @ H2 + hb2)
    float g = hb1[lane];
    for (int o = 0; o < 64; ++o) g = fmaf(feat[o], H1[o * 64 + lane], g);
    g = fmaxf(g, 0.f);
    float v = g * H2[lane];
    for (int off = 32; off > 0; off >>= 1) v += __shfl_down(v, off, 64);
    if (lane == 0) hurst[b] = 1.f / (1.f + expf(-(v + hb2[0])));
}

extern "C" void kernel_launch(void* const* d_in, const int* in_sizes, int n_in,
                              void* d_out, int out_size, void* d_ws, size_t ws_size,
                              hipStream_t stream)
{
    const float* t   = (const float*)d_in[0];
    const float* y0  = (const float*)d_in[1];
    const float* W1  = (const float*)d_in[2];
    const float* b1  = (const float*)d_in[3];
    const float* W2  = (const float*)d_in[4];
    const float* b2  = (const float*)d_in[5];
    const float* W3  = (const float*)d_in[6];
    const float* b3  = (const float*)d_in[7];
    const float* W4  = (const float*)d_in[8];
    const float* b4  = (const float*)d_in[9];
    const float* K3  = (const float*)d_in[10];
    const float* c3  = (const float*)d_in[11];
    const float* K5  = (const float*)d_in[12];
    const float* c5  = (const float*)d_in[13];
    const float* K7  = (const float*)d_in[14];
    const float* c7  = (const float*)d_in[15];
    const float* K11 = (const float*)d_in[16];
    const float* c11 = (const float*)d_in[17];
    const float* H1  = (const float*)d_in[18];
    const float* hb1 = (const float*)d_in[19];
    const float* H2  = (const float*)d_in[20];
    const float* hb2 = (const float*)d_in[21];

    float* out = (float*)d_out;
    float* ws  = (float*)d_ws;
    float* rhs      = ws;
    float* dtp      = ws + 524288;
    float* chunksum = ws + 1048576;
    float* chunkoff = ws + 1052672;
    float* Gd       = ws + 1056768;

    hipLaunchKernelGGL(k_rhs, dim3(256), dim3(256), 0, stream,
                       t, W1, b1, W2, b2, W3, b3, W4, b4, rhs);
    hipLaunchKernelGGL(k_csum, dim3(NCH), dim3(64), 0, stream, rhs, chunksum);
    hipLaunchKernelGGL(k_scan, dim3(1), dim3(64), 0, stream, chunksum, chunkoff, Gd);
    hipLaunchKernelGGL(k_dtp, dim3(NCH), dim3(64), 0, stream, t, rhs, chunkoff, dtp, Gd);
    hipLaunchKernelGGL(k_sol, dim3(2048), dim3(256), 0, stream,
                       (const float4*)y0, (const float4*)dtp, (float4*)out);
    hipLaunchKernelGGL(k_feat, dim3(BB), dim3(64), 0, stream,
                       y0, dtp, Gd, K3, c3, K5, c5, K7, c7, K11, c11,
                       H1, hb1, H2, hb2, out + (size_t)BB * SS * DD);
}

// Round 3
// 267.010 us; speedup vs baseline: 1.0365x; 1.0365x over previous
//
#include <hip/hip_runtime.h>
#include <cmath>

// Problem constants
#define SS 8192
#define BB 64
#define DD 64
#define CHK 64          // samples per chunk
#define NCHK 128        // SS / CHK

// ws layout (floats), all 16B-aligned:
//   lc   [SS][64]    @ 0       (524288)  dt * local inclusive cumsum within chunk
//   T    [NCHK][64]  @ 524288  (8192)    dt * chunk totals
//   L    [NCHK][64]  @ 532480  (8192)    sum over chunk of lc
//   off  [NCHK][64]  @ 540672  (8192)    exclusive scan of T (dt-scaled)
//   Gd   [64]        @ 548864  (64)      sum_s dtp[s][i]
//   hsts [12][64]    @ 548928  (768)     rows 0..5 = hs[d], rows 6..11 = ts[d]

// ---------------- Kernel A: MLP rhs + chunk-local cumsum + chunk stats ----------------
// 128 blocks x 128 threads. Block c handles samples s = c*64 + lane.
// Wave w (0/1) computes output-neuron half of each layer; sample-per-lane.
__global__ __launch_bounds__(128) void k_rhs(
    const float* __restrict__ t,
    const float* __restrict__ W1, const float* __restrict__ b1,
    const float* __restrict__ W2, const float* __restrict__ b2,
    const float* __restrict__ W3, const float* __restrict__ b3,
    const float* __restrict__ W4, const float* __restrict__ b4,
    float* __restrict__ lc, float* __restrict__ Tc, float* __restrict__ Lc)
{
    __shared__ float sW1[64], sb1[64], sb2[128], sb3[64], sb4[64];
    __shared__ float sW2[64 * 128];   // 32 KB
    __shared__ float sW3[128 * 64];   // 32 KB
    __shared__ float sW4[64 * 64];    // 16 KB
    __shared__ float xbuf[2 * 64 * 65];  // 33.3 KB, reused: h1/X2 -> X3 -> R

    const int tid = threadIdx.x;
    for (int i = tid; i < 64; i += 128) { sW1[i] = W1[i]; sb1[i] = b1[i]; sb3[i] = b3[i]; sb4[i] = b4[i]; }
    for (int i = tid; i < 128; i += 128) sb2[i] = b2[i];
    for (int i = tid; i < 64 * 128; i += 128) { sW2[i] = W2[i]; sW3[i] = W3[i]; }
    for (int i = tid; i < 64 * 64; i += 128) sW4[i] = W4[i];
    __syncthreads();                                   // B1

    const int w = tid >> 6, lane = tid & 63;
    const int c = blockIdx.x;
    const int s = c * CHK + lane;
    const float dtv = t[1] - t[0];
    const float tv = t[s];           // t row 0 (identical across batch)

    // layer1: full h1 per lane -> own row of xbuf (stride 65, 2-way banks)
    float* myrow = &xbuf[(w * 64 + lane) * 65];
    for (int j = 0; j < 64; ++j)
        myrow[j] = tanhf(fmaf(tv, sW1[j], sb1[j]));

    // layer2: this wave's 64 cols (col = w*64 + j2); weights = uniform b128 broadcasts
    float acc2[64];
    #pragma unroll
    for (int j2 = 0; j2 < 64; ++j2) acc2[j2] = sb2[w * 64 + j2];
    for (int i = 0; i < 64; ++i) {
        const float h = myrow[i];                      // own h1 (same-lane RAW, compiler waits)
        const float* wp = &sW2[i * 128 + w * 64];
        #pragma unroll
        for (int j2 = 0; j2 < 64; ++j2) acc2[j2] = fmaf(h, wp[j2], acc2[j2]);
    }
    // tanh + overwrite own row with h2-half (X2)
    #pragma unroll
    for (int j2 = 0; j2 < 64; ++j2) myrow[j2] = tanhf(acc2[j2]);
    __syncthreads();                                   // B2: X2 visible

    // layer3: this wave's 32 cols (col = w*32 + j3); h2 (all 128) from LDS
    float acc3[32];
    #pragma unroll
    for (int j3 = 0; j3 < 32; ++j3) acc3[j3] = sb3[w * 32 + j3];
    for (int i2 = 0; i2 < 128; ++i2) {
        const float h = xbuf[((i2 >> 6) * 64 + lane) * 65 + (i2 & 63)];
        const float* wp = &sW3[i2 * 64 + w * 32];
        #pragma unroll
        for (int j3 = 0; j3 < 32; ++j3) acc3[j3] = fmaf(h, wp[j3], acc3[j3]);
    }
    __syncthreads();                                   // B3: everyone done reading X2
    // tanh -> X3 at stride 33 (2-way banks)
    #pragma unroll
    for (int j3 = 0; j3 < 32; ++j3) xbuf[(w * 64 + lane) * 33 + j3] = tanhf(acc3[j3]);
    __syncthreads();                                   // B4: X3 visible

    // layer4: this wave's 32 cols (col = w*32 + j4); h3 (all 64) from LDS
    float acc4[32];
    #pragma unroll
    for (int j4 = 0; j4 < 32; ++j4) acc4[j4] = sb4[w * 32 + j4];
    for (int i3 = 0; i3 < 64; ++i3) {
        const float h = xbuf[((i3 >> 5) * 64 + lane) * 33 + (i3 & 31)];
        const float* wp = &sW4[i3 * 64 + w * 32];
        #pragma unroll
        for (int j4 = 0; j4 < 32; ++j4) acc4[j4] = fmaf(h, wp[j4], acc4[j4]);
    }
    __syncthreads();                                   // B5: X3 reads done

    // rhs[0] := 0 (reference: cumsum starts at s=1)
    if (s == 0) {
        #pragma unroll
        for (int j4 = 0; j4 < 32; ++j4) acc4[j4] = 0.f;
    }
    // write rhs rows R[sample][col] at stride 65
    #pragma unroll
    for (int j4 = 0; j4 < 32; ++j4) xbuf[lane * 65 + w * 32 + j4] = acc4[j4];
    __syncthreads();                                   // B6: R visible

    // chunk-local inclusive cumsum, dt-scaled (wave 0; lane = column i)
    if (w == 0) {
        float run = 0.f, Ls = 0.f;
        for (int j = 0; j < CHK; ++j) {
            run += xbuf[j * 65 + lane];
            const float v = dtv * run;
            lc[(c * CHK + j) * 64 + lane] = v;         // coalesced
            Ls += v;
        }
        Tc[c * 64 + lane] = dtv * run;
        Lc[c * 64 + lane] = Ls;
    }
}

// ---------------- Kernel B: chunk-offset scan + Gd + head/tail prefix sums ----------------
__global__ __launch_bounds__(64) void k_scan(
    const float* __restrict__ Tc, const float* __restrict__ Lc, const float* __restrict__ lc,
    float* __restrict__ off, float* __restrict__ Gd, float* __restrict__ hsts)
{
    const int i = threadIdx.x;
    float run = 0.f, g = 0.f, offL = 0.f;
    for (int c = 0; c < NCHK; ++c) {
        off[c * 64 + i] = run;
        if (c == NCHK - 1) offL = run;
        g += Lc[c * 64 + i] + (float)CHK * run;
        run += Tc[c * 64 + i];
    }
    Gd[i] = g;
    // hs[d] = sum_{e=0..d-1} dtp[e]  (chunk 0: dtp[e] = lc[e])
    float r2 = 0.f;
    hsts[i] = 0.f;                       // hs[0]
    for (int d = 1; d <= 5; ++d) { r2 += lc[(d - 1) * 64 + i]; hsts[d * 64 + i] = r2; }
    // ts[d] = sum_{e=1..d} dtp[S-e]  (last chunk: dtp = offL + lc)
    r2 = 0.f;
    hsts[6 * 64 + i] = 0.f;              // ts[0]
    for (int d = 1; d <= 5; ++d) { r2 += offL + lc[(SS - d) * 64 + i]; hsts[(6 + d) * 64 + i] = r2; }
}

// ---------------- Kernel C: sol[b,s,:] = y0[b,:] + off[c(s),:] + lc[s,:] ----------------
__global__ __launch_bounds__(256) void k_sol(const float4* __restrict__ y0,
                                             const float4* __restrict__ lc,
                                             const float4* __restrict__ off,
                                             float4* __restrict__ out)
{
    const int total4 = BB * SS * 16;   // 8388608
    for (int idx = blockIdx.x * 256 + threadIdx.x; idx < total4; idx += gridDim.x * 256) {
        const int i4 = idx & 15;
        const int s  = (idx >> 4) & (SS - 1);
        const int b  = idx >> 17;
        const int c  = s >> 6;
        const float4 y = y0[b * 16 + i4];
        const float4 p = lc[s * 16 + i4];
        const float4 f = off[c * 16 + i4];
        float4 o;
        o.x = y.x + f.x + p.x; o.y = y.y + f.y + p.y;
        o.z = y.z + f.z + p.z; o.w = y.w + f.w + p.w;
        out[idx] = o;
    }
}

// ---------------- Kernel D: analytic conv-mean features (coalesced matvec) + hurst ----------------
__global__ __launch_bounds__(256) void k_feat(
    const float* __restrict__ y0, const float* __restrict__ Gd, const float* __restrict__ hsts,
    const float* __restrict__ K3, const float* __restrict__ c3,
    const float* __restrict__ K5, const float* __restrict__ c5,
    const float* __restrict__ K7, const float* __restrict__ c7,
    const float* __restrict__ K11, const float* __restrict__ c11,
    const float* __restrict__ H1, const float* __restrict__ hb1,
    const float* __restrict__ H2, const float* __restrict__ hb2,
    float* __restrict__ hurst)
{
    __shared__ float tot[64], sy0[64], shts[12 * 64], V[1664], feat[64];
    const int b = blockIdx.x, tid = threadIdx.x;
    const int wv = tid >> 6, lane = tid & 63;

    if (tid < 64) { sy0[tid] = y0[b * 64 + tid]; tot[tid] = (float)SS * sy0[tid] + Gd[tid]; }
    for (int n = tid; n < 12 * 64; n += 256) shts[n] = hsts[n];
    __syncthreads();

    // V[n] = tot[i] - corr(d, i), n flattened over (kn, i, j)
    for (int n = tid; n < 1664; n += 256) {
        int base, k;
        if (n < 192)      { base = 0;   k = 3; }
        else if (n < 512) { base = 192; k = 5; }
        else if (n < 960) { base = 512; k = 7; }
        else              { base = 960; k = 11; }
        const int m = n - base, i = m / k, j = m - i * k, d = j - (k >> 1);
        float corr = 0.f;
        if (d > 0)      corr = (float)d * sy0[i] + shts[d * 64 + i];
        else if (d < 0) corr = (float)(-d) * sy0[i] + shts[(6 - d) * 64 + i];
        V[n] = tot[i] - corr;
    }
    __syncthreads();

    // feat[o] = 0.25 * ( dot(Kcat[o], V)/S + c3[o]+c5[o]+c7[o]+c11[o] )
    for (int q = 0; q < 16; ++q) {
        const int o = wv * 16 + q;
        float acc = 0.f;
        #pragma unroll
        for (int r = 0; r < 3; ++r)  { const int m = r * 64 + lane; acc = fmaf(K3[o * 192 + m],  V[m],        acc); }
        #pragma unroll
        for (int r = 0; r < 5; ++r)  { const int m = r * 64 + lane; acc = fmaf(K5[o * 320 + m],  V[192 + m],  acc); }
        #pragma unroll
        for (int r = 0; r < 7; ++r)  { const int m = r * 64 + lane; acc = fmaf(K7[o * 448 + m],  V[512 + m],  acc); }
        #pragma unroll
        for (int r = 0; r < 11; ++r) { const int m = r * 64 + lane; acc = fmaf(K11[o * 704 + m], V[960 + m],  acc); }
        #pragma unroll
        for (int d = 32; d; d >>= 1) acc += __shfl_xor(acc, d);
        if (lane == 0) {
            const float cb = c3[o] + c5[o] + c7[o] + c11[o];
            feat[o] = 0.25f * (acc * (1.0f / (float)SS) + cb);
        }
    }
    __syncthreads();

    if (tid < 64) {
        float g = hb1[lane];
        for (int o = 0; o < 64; ++o) g = fmaf(feat[o], H1[o * 64 + lane], g);
        g = fmaxf(g, 0.f);
        float v = g * H2[lane];
        #pragma unroll
        for (int d = 32; d; d >>= 1) v += __shfl_xor(v, d);
        if (lane == 0) hurst[b] = 1.f / (1.f + expf(-(v + hb2[0])));
    }
}

extern "C" void kernel_launch(void* const* d_in, const int* in_sizes, int n_in,
                              void* d_out, int out_size, void* d_ws, size_t ws_size,
                              hipStream_t stream)
{
    const float* t   = (const float*)d_in[0];
    const float* y0  = (const float*)d_in[1];
    const float* W1  = (const float*)d_in[2];
    const float* b1  = (const float*)d_in[3];
    const float* W2  = (const float*)d_in[4];
    const float* b2  = (const float*)d_in[5];
    const float* W3  = (const float*)d_in[6];
    const float* b3  = (const float*)d_in[7];
    const float* W4  = (const float*)d_in[8];
    const float* b4  = (const float*)d_in[9];
    const float* K3  = (const float*)d_in[10];
    const float* c3  = (const float*)d_in[11];
    const float* K5  = (const float*)d_in[12];
    const float* c5  = (const float*)d_in[13];
    const float* K7  = (const float*)d_in[14];
    const float* c7  = (const float*)d_in[15];
    const float* K11 = (const float*)d_in[16];
    const float* c11 = (const float*)d_in[17];
    const float* H1  = (const float*)d_in[18];
    const float* hb1 = (const float*)d_in[19];
    const float* H2  = (const float*)d_in[20];
    const float* hb2 = (const float*)d_in[21];

    float* out = (float*)d_out;
    float* ws  = (float*)d_ws;
    float* lc   = ws;
    float* Tc   = ws + 524288;
    float* Lc   = ws + 532480;
    float* off  = ws + 540672;
    float* Gd   = ws + 548864;
    float* hsts = ws + 548928;

    hipLaunchKernelGGL(k_rhs, dim3(NCHK), dim3(128), 0, stream,
                       t, W1, b1, W2, b2, W3, b3, W4, b4, lc, Tc, Lc);
    hipLaunchKernelGGL(k_scan, dim3(1), dim3(64), 0, stream, Tc, Lc, lc, off, Gd, hsts);
    hipLaunchKernelGGL(k_sol, dim3(2048), dim3(256), 0, stream,
                       (const float4*)y0, (const float4*)lc, (const float4*)off, (float4*)out);
    hipLaunchKernelGGL(k_feat, dim3(BB), dim3(256), 0, stream,
                       y0, Gd, hsts, K3, c3, K5, c5, K7, c7, K11, c11,
                       H1, hb1, H2, hb2, out + (size_t)BB * SS * DD);
}

// Round 4
// 228.984 us; speedup vs baseline: 1.2086x; 1.1661x over previous
//
#include <hip/hip_runtime.h>
#include <cmath>

// Problem constants
#define SS 8192
#define BB 64
#define DD 64
#define CHK 64          // samples per chunk
#define NCHK 128        // SS / CHK

// ws layout (floats):
//   lc   [SS][64]    @ 0       (524288)  dt * local inclusive cumsum within chunk
//   T    [NCHK][64]  @ 524288  (8192)    dt * chunk totals
//   L    [NCHK][64]  @ 532480  (8192)    sum over chunk of lc
//   off  [NCHK][64]  @ 540672  (8192)    exclusive scan of T (dt-scaled)
//   Gd   [64]        @ 548864  (64)      sum_s dtp[s][i]
//   hsts [12][64]    @ 548928  (768)     rows 0..5 = hs[d], rows 6..11 = ts[d]

// ---------------- Kernel A: MLP rhs + chunk-local cumsum ----------------
// 128 blocks x 512 threads (8 waves). Block c handles samples s = c*64 + lane.
// All 8 waves share the same 64 samples (lane = sample); wave w owns an
// output-neuron slice of each layer, so weight reads are wave-uniform LDS
// broadcasts and activations are stored ONCE per sample.
__global__ __launch_bounds__(512) void k_rhs(
    const float* __restrict__ t,
    const float* __restrict__ W1, const float* __restrict__ b1,
    const float* __restrict__ W2, const float* __restrict__ b2,
    const float* __restrict__ W3, const float* __restrict__ b3,
    const float* __restrict__ W4, const float* __restrict__ b4,
    float* __restrict__ lc, float* __restrict__ Tc, float* __restrict__ Lc)
{
    __shared__ float sW1[64], sb1[64], sb2[128], sb3[64], sb4[64];
    __shared__ float sW2[64 * 128];   // 32 KB
    __shared__ float sW3[128 * 64];   // 32 KB
    __shared__ float sW4[64 * 64];    // 16 KB
    __shared__ float HA[64 * 65];     // h1 (stride 65 -> 2-way banks, free); reused for rhs R
    __shared__ float XB[64 * 129];    // h2 (stride 129 -> 2-way banks)
    __shared__ float XC[64 * 65];     // h3
    // total ~146.5 KB -> 1 block/CU, 8 waves/CU

    const int tid = threadIdx.x;
    for (int i = tid; i < 64; i += 512) { sW1[i] = W1[i]; sb1[i] = b1[i]; sb3[i] = b3[i]; sb4[i] = b4[i]; }
    if (tid < 128) sb2[tid] = b2[tid];
    for (int i = tid; i < 64 * 128; i += 512) { sW2[i] = W2[i]; sW3[i] = W3[i]; }
    for (int i = tid; i < 64 * 64; i += 512) sW4[i] = W4[i];
    __syncthreads();

    const int w = tid >> 6, lane = tid & 63;
    const int c = blockIdx.x;
    const int s = c * CHK + lane;
    const float dtv = t[1] - t[0];
    const float tv = t[s];           // t row 0 (identical across batch)

    // layer1: wave w computes h1 cols w*8..w*8+7 for its lane's sample
    #pragma unroll
    for (int j = 0; j < 8; ++j) {
        const int col = w * 8 + j;
        HA[lane * 65 + col] = tanhf(fmaf(tv, sW1[col], sb1[col]));
    }
    __syncthreads();

    // layer2: wave w -> cols [w*16, w*16+16)
    float acc2[16];
    #pragma unroll
    for (int j = 0; j < 16; ++j) acc2[j] = sb2[w * 16 + j];
    for (int i = 0; i < 64; ++i) {
        const float h = HA[lane * 65 + i];
        const float* wp = &sW2[i * 128 + w * 16];   // wave-uniform -> 4x b128 broadcast
        #pragma unroll
        for (int j = 0; j < 16; ++j) acc2[j] = fmaf(h, wp[j], acc2[j]);
    }
    #pragma unroll
    for (int j = 0; j < 16; ++j) XB[lane * 129 + w * 16 + j] = tanhf(acc2[j]);
    __syncthreads();

    // layer3: wave w -> cols [w*8, w*8+8)
    float acc3[8];
    #pragma unroll
    for (int j = 0; j < 8; ++j) acc3[j] = sb3[w * 8 + j];
    for (int i = 0; i < 128; ++i) {
        const float h = XB[lane * 129 + i];
        const float* wp = &sW3[i * 64 + w * 8];
        #pragma unroll
        for (int j = 0; j < 8; ++j) acc3[j] = fmaf(h, wp[j], acc3[j]);
    }
    #pragma unroll
    for (int j = 0; j < 8; ++j) XC[lane * 65 + w * 8 + j] = tanhf(acc3[j]);
    __syncthreads();

    // layer4: wave w -> cols [w*8, w*8+8)
    float acc4[8];
    #pragma unroll
    for (int j = 0; j < 8; ++j) acc4[j] = sb4[w * 8 + j];
    for (int i = 0; i < 64; ++i) {
        const float h = XC[lane * 65 + i];
        const float* wp = &sW4[i * 64 + w * 8];
        #pragma unroll
        for (int j = 0; j < 8; ++j) acc4[j] = fmaf(h, wp[j], acc4[j]);
    }
    // rhs row s=0 := 0 (reference cumsum starts at s=1); lane 0 of every wave
    if (s == 0) {
        #pragma unroll
        for (int j = 0; j < 8; ++j) acc4[j] = 0.f;
    }
    // write rhs R into HA (h1 reads all completed before the post-l2 barrier)
    #pragma unroll
    for (int j = 0; j < 8; ++j) HA[lane * 65 + w * 8 + j] = acc4[j];
    __syncthreads();

    // chunk-local inclusive cumsum, dt-scaled (wave 0; lane = column)
    if (w == 0) {
        float run = 0.f, Ls = 0.f;
        for (int jj = 0; jj < CHK; ++jj) {
            run += HA[jj * 65 + lane];
            const float v = dtv * run;
            lc[(c * CHK + jj) * 64 + lane] = v;        // coalesced
            Ls += v;
        }
        Tc[c * 64 + lane] = dtv * run;
        Lc[c * 64 + lane] = Ls;
    }
}

// ---------------- Kernel B: parallel chunk-offset scan + Gd + head/tail sums ----------------
// 1 block x 1024 threads: col = tid&63, grp = tid>>6 (16 groups x 8 chunks).
__global__ __launch_bounds__(1024) void k_scan(
    const float* __restrict__ Tc, const float* __restrict__ Lc, const float* __restrict__ lcg,
    float* __restrict__ off, float* __restrict__ Gd, float* __restrict__ hsts)
{
    __shared__ float gsum[16 * 65];
    __shared__ float offL[64];
    const int tid = threadIdx.x;
    const int col = tid & 63, grp = tid >> 6;   // grp is wave-uniform

    float Tl[8];
    float localSum = 0.f;
    #pragma unroll
    for (int k = 0; k < 8; ++k) { Tl[k] = Tc[(grp * 8 + k) * 64 + col]; localSum += Tl[k]; }
    gsum[grp * 65 + col] = localSum;
    __syncthreads();

    float base = 0.f;
    for (int g = 0; g < grp; ++g) base += gsum[g * 65 + col];   // wave-uniform trip count
    __syncthreads();

    float run = base, gpart = 0.f;
    #pragma unroll
    for (int k = 0; k < 8; ++k) {
        const int cc = grp * 8 + k;
        off[cc * 64 + col] = run;                  // coalesced across col
        if (cc == NCHK - 1) offL[col] = run;
        gpart += Lc[cc * 64 + col] + (float)CHK * run;
        run += Tl[k];
    }
    gsum[grp * 65 + col] = gpart;
    __syncthreads();

    if (grp == 0) {
        float g = 0.f;
        #pragma unroll
        for (int gg = 0; gg < 16; ++gg) g += gsum[gg * 65 + col];
        Gd[col] = g;
    }
    if (grp == 1) {
        // hs[d] = sum_{e=0..d-1} dtp[e]; chunk 0 offset is 0 -> dtp[e] = lc[e]
        float r2 = 0.f;
        hsts[col] = 0.f;
        for (int d = 1; d <= 5; ++d) { r2 += lcg[(d - 1) * 64 + col]; hsts[d * 64 + col] = r2; }
    }
    if (grp == 2) {
        // ts[d] = sum_{e=1..d} dtp[S-e]; dtp[S-e] = off[127] + lc[S-e]
        const float oL = offL[col];
        float r2 = 0.f;
        hsts[6 * 64 + col] = 0.f;
        for (int d = 1; d <= 5; ++d) { r2 += oL + lcg[(SS - d) * 64 + col]; hsts[(6 + d) * 64 + col] = r2; }
    }
}

// ---------------- Kernel C: sol[b,s,:] = y0[b,:] + off[c(s),:] + lc[s,:] ----------------
__global__ __launch_bounds__(256) void k_sol(const float4* __restrict__ y0,
                                             const float4* __restrict__ lc,
                                             const float4* __restrict__ off,
                                             float4* __restrict__ out)
{
    const int total4 = BB * SS * 16;   // 8388608
    for (int idx = blockIdx.x * 256 + threadIdx.x; idx < total4; idx += gridDim.x * 256) {
        const int i4 = idx & 15;
        const int s  = (idx >> 4) & (SS - 1);
        const int b  = idx >> 17;
        const int c  = s >> 6;
        const float4 y = y0[b * 16 + i4];
        const float4 p = lc[s * 16 + i4];
        const float4 f = off[c * 16 + i4];
        float4 o;
        o.x = y.x + f.x + p.x; o.y = y.y + f.y + p.y;
        o.z = y.z + f.z + p.z; o.w = y.w + f.w + p.w;
        out[idx] = o;
    }
}

// ---------------- Kernel D: analytic conv-mean features (coalesced matvec) + hurst ----------------
__global__ __launch_bounds__(256) void k_feat(
    const float* __restrict__ y0, const float* __restrict__ Gd, const float* __restrict__ hsts,
    const float* __restrict__ K3, const float* __restrict__ c3,
    const float* __restrict__ K5, const float* __restrict__ c5,
    const float* __restrict__ K7, const float* __restrict__ c7,
    const float* __restrict__ K11, const float* __restrict__ c11,
    const float* __restrict__ H1, const float* __restrict__ hb1,
    const float* __restrict__ H2, const float* __restrict__ hb2,
    float* __restrict__ hurst)
{
    __shared__ float tot[64], sy0[64], shts[12 * 64], V[1664], feat[64];
    const int b = blockIdx.x, tid = threadIdx.x;
    const int wv = tid >> 6, lane = tid & 63;

    if (tid < 64) { sy0[tid] = y0[b * 64 + tid]; tot[tid] = (float)SS * sy0[tid] + Gd[tid]; }
    for (int n = tid; n < 12 * 64; n += 256) shts[n] = hsts[n];
    __syncthreads();

    // V[n] = tot[i] - corr(d, i), n flattened over (kn, i, j)
    for (int n = tid; n < 1664; n += 256) {
        int base, k;
        if (n < 192)      { base = 0;   k = 3; }
        else if (n < 512) { base = 192; k = 5; }
        else if (n < 960) { base = 512; k = 7; }
        else              { base = 960; k = 11; }
        const int m = n - base, i = m / k, j = m - i * k, d = j - (k >> 1);
        float corr = 0.f;
        if (d > 0)      corr = (float)d * sy0[i] + shts[d * 64 + i];
        else if (d < 0) corr = (float)(-d) * sy0[i] + shts[(6 - d) * 64 + i];
        V[n] = tot[i] - corr;
    }
    __syncthreads();

    // feat[o] = 0.25 * ( dot(Kcat[o], V)/S + c3[o]+c5[o]+c7[o]+c11[o] )
    for (int q = 0; q < 16; ++q) {
        const int o = wv * 16 + q;
        float acc = 0.f;
        #pragma unroll
        for (int r = 0; r < 3; ++r)  { const int m = r * 64 + lane; acc = fmaf(K3[o * 192 + m],  V[m],        acc); }
        #pragma unroll
        for (int r = 0; r < 5; ++r)  { const int m = r * 64 + lane; acc = fmaf(K5[o * 320 + m],  V[192 + m],  acc); }
        #pragma unroll
        for (int r = 0; r < 7; ++r)  { const int m = r * 64 + lane; acc = fmaf(K7[o * 448 + m],  V[512 + m],  acc); }
        #pragma unroll
        for (int r = 0; r < 11; ++r) { const int m = r * 64 + lane; acc = fmaf(K11[o * 704 + m], V[960 + m],  acc); }
        #pragma unroll
        for (int d = 32; d; d >>= 1) acc += __shfl_xor(acc, d);
        if (lane == 0) {
            const float cb = c3[o] + c5[o] + c7[o] + c11[o];
            feat[o] = 0.25f * (acc * (1.0f / (float)SS) + cb);
        }
    }
    __syncthreads();

    if (tid < 64) {
        float g = hb1[lane];
        for (int o = 0; o < 64; ++o) g = fmaf(feat[o], H1[o * 64 + lane], g);
        g = fmaxf(g, 0.f);
        float v = g * H2[lane];
        #pragma unroll
        for (int d = 32; d; d >>= 1) v += __shfl_xor(v, d);
        if (lane == 0) hurst[b] = 1.f / (1.f + expf(-(v + hb2[0])));
    }
}

extern "C" void kernel_launch(void* const* d_in, const int* in_sizes, int n_in,
                              void* d_out, int out_size, void* d_ws, size_t ws_size,
                              hipStream_t stream)
{
    const float* t   = (const float*)d_in[0];
    const float* y0  = (const float*)d_in[1];
    const float* W1  = (const float*)d_in[2];
    const float* b1  = (const float*)d_in[3];
    const float* W2  = (const float*)d_in[4];
    const float* b2  = (const float*)d_in[5];
    const float* W3  = (const float*)d_in[6];
    const float* b3  = (const float*)d_in[7];
    const float* W4  = (const float*)d_in[8];
    const float* b4  = (const float*)d_in[9];
    const float* K3  = (const float*)d_in[10];
    const float* c3  = (const float*)d_in[11];
    const float* K5  = (const float*)d_in[12];
    const float* c5  = (const float*)d_in[13];
    const float* K7  = (const float*)d_in[14];
    const float* c7  = (const float*)d_in[15];
    const float* K11 = (const float*)d_in[16];
    const float* c11 = (const float*)d_in[17];
    const float* H1  = (const float*)d_in[18];
    const float* hb1 = (const float*)d_in[19];
    const float* H2  = (const float*)d_in[20];
    const float* hb2 = (const float*)d_in[21];

    float* out = (float*)d_out;
    float* ws  = (float*)d_ws;
    float* lc   = ws;
    float* Tc   = ws + 524288;
    float* Lc   = ws + 532480;
    float* off  = ws + 540672;
    float* Gd   = ws + 548864;
    float* hsts = ws + 548928;

    hipLaunchKernelGGL(k_rhs, dim3(NCHK), dim3(512), 0, stream,
                       t, W1, b1, W2, b2, W3, b3, W4, b4, lc, Tc, Lc);
    hipLaunchKernelGGL(k_scan, dim3(1), dim3(1024), 0, stream, Tc, Lc, lc, off, Gd, hsts);
    hipLaunchKernelGGL(k_sol, dim3(2048), dim3(256), 0, stream,
                       (const float4*)y0, (const float4*)lc, (const float4*)off, (float4*)out);
    hipLaunchKernelGGL(k_feat, dim3(BB), dim3(256), 0, stream,
                       y0, Gd, hsts, K3, c3, K5, c5, K7, c7, K11, c11,
                       H1, hb1, H2, hb2, out + (size_t)BB * SS * DD);
}